// Round 1
// baseline (569.767 us; speedup 1.0000x reference)
//
#include <hip/hip_runtime.h>
#include <hip/hip_bf16.h>
#include <math.h>

#define B__ 64
#define NTOK 512
#define CDIM 192
#define HEADS 6
#define HD 32
#define NW 16
#define T3 3375
#define HID 512

// ---------------- K1: CPB MLP -> tbl_t[6][3375] (16*sigmoid applied) ----------------
__global__ __launch_bounds__(512) void k_cpb(
    const float* __restrict__ rel_table, const float* __restrict__ w1,
    const float* __restrict__ b1, const float* __restrict__ w2,
    float* __restrict__ tbl_t) {
  int i = blockIdx.x;          // table row 0..3374
  int t = threadIdx.x;         // hidden unit 0..511
  float t0 = rel_table[i*3+0], t1 = rel_table[i*3+1], t2 = rel_table[i*3+2];
  float hval = fmaxf(t0*w1[t*3+0] + t1*w1[t*3+1] + t2*w1[t*3+2] + b1[t], 0.f);
  __shared__ float red[8][6];
  int wv = t >> 6, lane = t & 63;
  #pragma unroll
  for (int hh = 0; hh < 6; ++hh) {
    float p = hval * w2[hh*HID + t];
    #pragma unroll
    for (int off = 32; off > 0; off >>= 1) p += __shfl_down(p, off);
    if (lane == 0) red[wv][hh] = p;
  }
  __syncthreads();
  if (t < 6) {
    float s = 0.f;
    #pragma unroll
    for (int w8 = 0; w8 < 8; ++w8) s += red[w8][t];
    tbl_t[t*T3 + i] = 16.f / (1.f + __expf(-s));
  }
}

// ---------------- K2: expand bias table -> bias_t[h][m][n] ----------------
__global__ __launch_bounds__(256) void k_expand(
    const int* __restrict__ idx, const float* __restrict__ tbl_t,
    float* __restrict__ bias_t) {
  int g = blockIdx.x*256 + threadIdx.x;   // 0..262143
  int m = g >> 9, n = g & 511;
  int id = idx[n*512 + m];                // rel_index[n][m]
  #pragma unroll
  for (int hh = 0; hh < 6; ++hh)
    bias_t[hh*262144 + m*512 + n] = tbl_t[hh*T3 + id];
}

// ---------------- K3: transpose mask -> mask_t[w][m][n] ----------------
__global__ __launch_bounds__(256) void k_mask_t(
    const float* __restrict__ mask, float* __restrict__ mask_t) {
  __shared__ float tile[64][68];
  int w  = blockIdx.z;
  int tm = blockIdx.x*64, tn = blockIdx.y*64;
  const float* src = mask  + (size_t)w*262144;
  float*       dst = mask_t + (size_t)w*262144;
  int t = threadIdx.x;
  int r = t >> 4, c4 = (t & 15) * 4;
  for (int rr = r; rr < 64; rr += 16) {
    float4 v = *(const float4*)(src + (size_t)(tn + rr)*512 + tm + c4);
    tile[c4+0][rr] = v.x; tile[c4+1][rr] = v.y;
    tile[c4+2][rr] = v.z; tile[c4+3][rr] = v.w;
  }
  __syncthreads();
  for (int rr = r; rr < 64; rr += 16) {
    float4 v = *(const float4*)(&tile[rr][c4]);
    *(float4*)(dst + (size_t)(tm + rr)*512 + tn + c4) = v;
  }
}

// ---------------- K4: QKV GEMM + bias + q/k row-norm + logit scale ----------------
// x:[32768][192]  w:[576][192]  out: qn/kn/vv each [B][H][N][HD]
__global__ __launch_bounds__(192) void k_qkv(
    const float* __restrict__ x, const float* __restrict__ wq,
    const float* __restrict__ q_bias, const float* __restrict__ v_bias,
    const float* __restrict__ logit_scale,
    float* __restrict__ qn, float* __restrict__ kn, float* __restrict__ vv) {
  __shared__ float xs[16][200];
  int t  = threadIdx.x;            // 0..191 = column within each part
  int m0 = blockIdx.x * 16;
  // stage 16x192 x-tile (768 float4 / 192 threads = 4 each)
  #pragma unroll
  for (int i = 0; i < 4; ++i) {
    int fid = t + i*192;
    int r = fid / 48, k = (fid % 48) * 4;
    *(float4*)(&xs[r][k]) = *(const float4*)(x + (size_t)(m0 + r)*192 + k);
  }
  __syncthreads();

  float acc[3][16];
  #pragma unroll
  for (int p = 0; p < 3; ++p)
    #pragma unroll
    for (int r = 0; r < 16; ++r) acc[p][r] = 0.f;

  for (int kc = 0; kc < 12; ++kc) {
    int k0 = kc * 16;
    float wr[3][16];
    #pragma unroll
    for (int p = 0; p < 3; ++p) {
      const float* wp = wq + (size_t)(p*192 + t)*192 + k0;
      float4 a0 = *(const float4*)(wp+0);
      float4 a1 = *(const float4*)(wp+4);
      float4 a2 = *(const float4*)(wp+8);
      float4 a3 = *(const float4*)(wp+12);
      wr[p][0]=a0.x; wr[p][1]=a0.y; wr[p][2]=a0.z; wr[p][3]=a0.w;
      wr[p][4]=a1.x; wr[p][5]=a1.y; wr[p][6]=a1.z; wr[p][7]=a1.w;
      wr[p][8]=a2.x; wr[p][9]=a2.y; wr[p][10]=a2.z; wr[p][11]=a2.w;
      wr[p][12]=a3.x; wr[p][13]=a3.y; wr[p][14]=a3.z; wr[p][15]=a3.w;
    }
    #pragma unroll
    for (int r = 0; r < 16; ++r) {
      float xk[16];
      float4 x0 = *(const float4*)(&xs[r][k0+0]);
      float4 x1 = *(const float4*)(&xs[r][k0+4]);
      float4 x2 = *(const float4*)(&xs[r][k0+8]);
      float4 x3 = *(const float4*)(&xs[r][k0+12]);
      xk[0]=x0.x; xk[1]=x0.y; xk[2]=x0.z; xk[3]=x0.w;
      xk[4]=x1.x; xk[5]=x1.y; xk[6]=x1.z; xk[7]=x1.w;
      xk[8]=x2.x; xk[9]=x2.y; xk[10]=x2.z; xk[11]=x2.w;
      xk[12]=x3.x; xk[13]=x3.y; xk[14]=x3.z; xk[15]=x3.w;
      #pragma unroll
      for (int p = 0; p < 3; ++p)
        #pragma unroll
        for (int kk = 0; kk < 16; ++kk)
          acc[p][r] = fmaf(xk[kk], wr[p][kk], acc[p][r]);
    }
  }

  int hh = t >> 5, d = t & 31;
  float scaleq = __expf(fminf(logit_scale[hh], 4.6051702f));
  float qb = q_bias[t], vb = v_bias[t];
  #pragma unroll
  for (int r = 0; r < 16; ++r) {
    int m = m0 + r;
    int bb = m >> 9, n = m & 511;
    size_t base = ((((size_t)bb*HEADS + hh)*NTOK) + n)*HD + d;
    float qv = acc[0][r] + qb;
    float kv = acc[1][r];
    float vval = acc[2][r] + vb;
    float ssq = qv*qv, ssk = kv*kv;
    #pragma unroll
    for (int off = 16; off > 0; off >>= 1) {
      ssq += __shfl_xor(ssq, off, 32);
      ssk += __shfl_xor(ssk, off, 32);
    }
    float invq = 1.f / fmaxf(sqrtf(ssq), 1e-12f);
    float invk = 1.f / fmaxf(sqrtf(ssk), 1e-12f);
    qn[base] = qv * invq * scaleq;
    kn[base] = kv * invk;
    vv[base] = vval;
  }
}

// ---------------- K5: attention (online softmax), out -> d_out [b][n][h*32+d] ----------------
__global__ __launch_bounds__(256) void k_attn(
    const float* __restrict__ qn, const float* __restrict__ kn,
    const float* __restrict__ vv, const float* __restrict__ bias_t,
    const float* __restrict__ mask_t, float* __restrict__ out) {
  int b = blockIdx.z, h = blockIdx.y;
  int n = blockIdx.x*256 + threadIdx.x;
  int w = b & (NW-1);
  size_t headbase = (((size_t)b*HEADS + h)*NTOK)*HD;
  const float* qrow = qn + headbase + (size_t)n*HD;
  const float* kb = kn + headbase;
  const float* vb = vv + headbase;
  const float* bp = bias_t + (size_t)h*262144 + n;
  const float* mp = mask_t + (size_t)w*262144 + n;

  float q[32];
  #pragma unroll
  for (int d4 = 0; d4 < 8; ++d4) {
    float4 v = *(const float4*)(qrow + d4*4);
    q[d4*4+0]=v.x; q[d4*4+1]=v.y; q[d4*4+2]=v.z; q[d4*4+3]=v.w;
  }

  __shared__ float ks[64][32];
  __shared__ float vs[64][32];
  float acc[32];
  #pragma unroll
  for (int d = 0; d < 32; ++d) acc[d] = 0.f;
  float mmax = -1e30f, msum = 0.f;

  for (int ch = 0; ch < 8; ++ch) {
    __syncthreads();
    #pragma unroll
    for (int i = 0; i < 2; ++i) {
      int f = threadIdx.x + i*256;          // float4 id 0..511
      int r = f >> 3, c = (f & 7) * 4;
      *(float4*)(&ks[r][c]) = *(const float4*)(kb + (size_t)(ch*64 + r)*HD + c);
      *(float4*)(&vs[r][c]) = *(const float4*)(vb + (size_t)(ch*64 + r)*HD + c);
    }
    __syncthreads();

    float bm_next = bp[(size_t)(ch*64)*512] + mp[(size_t)(ch*64)*512];
    for (int j = 0; j < 64; ++j) {
      int m = ch*64 + j;
      float bm = bm_next;
      int mn = (m + 1 < 512) ? (m + 1) : 511;
      bm_next = bp[(size_t)mn*512] + mp[(size_t)mn*512];

      float s = 0.f;
      #pragma unroll
      for (int d4 = 0; d4 < 8; ++d4) {
        float4 kv4 = *(const float4*)(&ks[j][d4*4]);
        s = fmaf(q[d4*4+0], kv4.x, s);
        s = fmaf(q[d4*4+1], kv4.y, s);
        s = fmaf(q[d4*4+2], kv4.z, s);
        s = fmaf(q[d4*4+3], kv4.w, s);
      }
      float l = s + bm;
      if (l > mmax) {
        float corr = __expf(mmax - l);
        #pragma unroll
        for (int d = 0; d < 32; ++d) acc[d] *= corr;
        msum *= corr;
        mmax = l;
      }
      float p = __expf(l - mmax);
      msum += p;
      #pragma unroll
      for (int d4 = 0; d4 < 8; ++d4) {
        float4 vv4 = *(const float4*)(&vs[j][d4*4]);
        acc[d4*4+0] = fmaf(p, vv4.x, acc[d4*4+0]);
        acc[d4*4+1] = fmaf(p, vv4.y, acc[d4*4+1]);
        acc[d4*4+2] = fmaf(p, vv4.z, acc[d4*4+2]);
        acc[d4*4+3] = fmaf(p, vv4.w, acc[d4*4+3]);
      }
    }
  }
  float inv = 1.f / msum;
  float* op = out + ((size_t)b*NTOK + n)*CDIM + h*HD;
  #pragma unroll
  for (int d4 = 0; d4 < 8; ++d4) {
    float4 v;
    v.x = acc[d4*4+0]*inv; v.y = acc[d4*4+1]*inv;
    v.z = acc[d4*4+2]*inv; v.w = acc[d4*4+3]*inv;
    *(float4*)(op + d4*4) = v;
  }
}

// ---------------- K6: output projection, in-place on d_out ----------------
// y[m][c] = sum_k a[m][k]*W[c][k] + b[c];  a == out (rows staged to LDS first)
__global__ __launch_bounds__(192) void k_proj(
    float* __restrict__ a, const float* __restrict__ wp,
    const float* __restrict__ pb) {
  __shared__ float xs[32][200];
  int t  = threadIdx.x;
  int m0 = blockIdx.x * 32;
  #pragma unroll
  for (int i = 0; i < 8; ++i) {
    int fid = t + i*192;
    int r = fid / 48, k = (fid % 48) * 4;
    *(float4*)(&xs[r][k]) = *(const float4*)(a + (size_t)(m0 + r)*CDIM + k);
  }
  __syncthreads();

  int rg = t / 96;          // row group: rows rg*16 .. rg*16+15
  int c0 = t % 96;          // columns c0 and c0+96
  float acc[2][16];
  #pragma unroll
  for (int cc = 0; cc < 2; ++cc)
    #pragma unroll
    for (int r = 0; r < 16; ++r) acc[cc][r] = 0.f;

  for (int kc = 0; kc < 12; ++kc) {
    int k0 = kc * 16;
    float wr[2][16];
    #pragma unroll
    for (int cc = 0; cc < 2; ++cc) {
      const float* wrow = wp + (size_t)(c0 + cc*96)*CDIM + k0;
      float4 a0 = *(const float4*)(wrow+0);
      float4 a1 = *(const float4*)(wrow+4);
      float4 a2 = *(const float4*)(wrow+8);
      float4 a3 = *(const float4*)(wrow+12);
      wr[cc][0]=a0.x; wr[cc][1]=a0.y; wr[cc][2]=a0.z; wr[cc][3]=a0.w;
      wr[cc][4]=a1.x; wr[cc][5]=a1.y; wr[cc][6]=a1.z; wr[cc][7]=a1.w;
      wr[cc][8]=a2.x; wr[cc][9]=a2.y; wr[cc][10]=a2.z; wr[cc][11]=a2.w;
      wr[cc][12]=a3.x; wr[cc][13]=a3.y; wr[cc][14]=a3.z; wr[cc][15]=a3.w;
    }
    #pragma unroll
    for (int r = 0; r < 16; ++r) {
      int row = rg*16 + r;
      float xk[16];
      float4 x0 = *(const float4*)(&xs[row][k0+0]);
      float4 x1 = *(const float4*)(&xs[row][k0+4]);
      float4 x2 = *(const float4*)(&xs[row][k0+8]);
      float4 x3 = *(const float4*)(&xs[row][k0+12]);
      xk[0]=x0.x; xk[1]=x0.y; xk[2]=x0.z; xk[3]=x0.w;
      xk[4]=x1.x; xk[5]=x1.y; xk[6]=x1.z; xk[7]=x1.w;
      xk[8]=x2.x; xk[9]=x2.y; xk[10]=x2.z; xk[11]=x2.w;
      xk[12]=x3.x; xk[13]=x3.y; xk[14]=x3.z; xk[15]=x3.w;
      #pragma unroll
      for (int cc = 0; cc < 2; ++cc)
        #pragma unroll
        for (int kk = 0; kk < 16; ++kk)
          acc[cc][r] = fmaf(xk[kk], wr[cc][kk], acc[cc][r]);
    }
  }
  __syncthreads();
  #pragma unroll
  for (int cc = 0; cc < 2; ++cc) {
    int c = c0 + cc*96;
    float bias = pb[c];
    #pragma unroll
    for (int r = 0; r < 16; ++r) {
      int row = m0 + rg*16 + r;
      a[(size_t)row*CDIM + c] = acc[cc][r] + bias;
    }
  }
}

extern "C" void kernel_launch(void* const* d_in, const int* in_sizes, int n_in,
                              void* d_out, int out_size, void* d_ws, size_t ws_size,
                              hipStream_t stream) {
  const float* x           = (const float*)d_in[0];
  const float* mask        = (const float*)d_in[1];
  const float* qkv_w       = (const float*)d_in[2];
  const float* q_bias      = (const float*)d_in[3];
  const float* v_bias      = (const float*)d_in[4];
  const float* logit_scale = (const float*)d_in[5];
  const float* cpb_w1      = (const float*)d_in[6];
  const float* cpb_b1      = (const float*)d_in[7];
  const float* cpb_w2      = (const float*)d_in[8];
  const float* proj_w      = (const float*)d_in[9];
  const float* proj_b      = (const float*)d_in[10];
  const float* rel_table   = (const float*)d_in[11];
  const int*   rel_index   = (const int*)d_in[12];
  float* out = (float*)d_out;

  float* wsf    = (float*)d_ws;
  float* tbl_t  = wsf;                       // 6*3375 -> reserve 20480
  float* bias_t = wsf + 20480;               // 6*512*512   = 1572864
  float* mask_t = bias_t + 1572864;          // 16*512*512  = 4194304
  float* qn     = mask_t + 4194304;          // 64*6*512*32 = 6291456
  float* kn     = qn + 6291456;
  float* vv     = kn + 6291456;
  // total: 24,662,016 floats ~= 98.6 MB of workspace

  k_cpb<<<T3, 512, 0, stream>>>(rel_table, cpb_w1, cpb_b1, cpb_w2, tbl_t);
  k_expand<<<1024, 256, 0, stream>>>(rel_index, tbl_t, bias_t);
  k_mask_t<<<dim3(8, 8, NW), 256, 0, stream>>>(mask, mask_t);
  k_qkv<<<2048, 192, 0, stream>>>(x, qkv_w, q_bias, v_bias, logit_scale, qn, kn, vv);
  k_attn<<<dim3(2, HEADS, B__), 256, 0, stream>>>(qn, kn, vv, bias_t, mask_t, out);
  k_proj<<<1024, 192, 0, stream>>>(out, proj_w, proj_b);
}

// Round 3
// 410.405 us; speedup vs baseline: 1.3883x; 1.3883x over previous
//
#include <hip/hip_runtime.h>
#include <hip/hip_bf16.h>
#include <math.h>

#define B__ 64
#define NTOK 512
#define CDIM 192
#define HEADS 6
#define HD 32
#define NW 16
#define T3 3375
#define HID 512

typedef _Float16 f16x8 __attribute__((ext_vector_type(8)));
typedef _Float16 f16x4 __attribute__((ext_vector_type(4)));
typedef float    f32x4 __attribute__((ext_vector_type(4)));

// ---------------- K1: CPB MLP -> tbl_t[6][3375] (16*sigmoid applied) ----------------
__global__ __launch_bounds__(512) void k_cpb(
    const float* __restrict__ rel_table, const float* __restrict__ w1,
    const float* __restrict__ b1, const float* __restrict__ w2,
    float* __restrict__ tbl_t) {
  int i = blockIdx.x;          // table row 0..3374
  int t = threadIdx.x;         // hidden unit 0..511
  float t0 = rel_table[i*3+0], t1 = rel_table[i*3+1], t2 = rel_table[i*3+2];
  float hval = fmaxf(t0*w1[t*3+0] + t1*w1[t*3+1] + t2*w1[t*3+2] + b1[t], 0.f);
  __shared__ float red[8][6];
  int wv = t >> 6, lane = t & 63;
  #pragma unroll
  for (int hh = 0; hh < 6; ++hh) {
    float p = hval * w2[hh*HID + t];
    #pragma unroll
    for (int off = 32; off > 0; off >>= 1) p += __shfl_down(p, off);
    if (lane == 0) red[wv][hh] = p;
  }
  __syncthreads();
  if (t < 6) {
    float s = 0.f;
    #pragma unroll
    for (int w8 = 0; w8 < 8; ++w8) s += red[w8][t];
    tbl_t[t*T3 + i] = 16.f / (1.f + __expf(-s));
  }
}

// ---------------- K2: bias table -> MFMA-fragment layout, fp16 ----------------
// bias_f[h][qt][kt][lane][r] = 16*sigmoid(tbl[idx[q][k]][h]), q=qt*16+(l>>4)*4+r, k=kt*16+(l&15)
__global__ __launch_bounds__(64) void k_biasf(
    const int* __restrict__ idx, const float* __restrict__ tbl_t,
    _Float16* __restrict__ bias_f) {
  int bx = blockIdx.x;              // qt*32+kt, 0..1023
  int h  = blockIdx.y;
  int l  = threadIdx.x;
  int qt = bx >> 5, kt = bx & 31;
  int k  = kt*16 + (l & 15);
  int qb = qt*16 + (l >> 4)*4;
  f16x4 v;
  #pragma unroll
  for (int r = 0; r < 4; ++r) {
    int id = idx[(qb + r)*512 + k];
    v[r] = (_Float16)tbl_t[h*T3 + id];
  }
  *(f16x4*)(bias_f + ((size_t)(h*1024 + bx)*64 + l)*4) = v;
}

// ---------------- K3: mask -> MFMA-fragment layout, fp16 ----------------
__global__ __launch_bounds__(64) void k_maskf(
    const float* __restrict__ mask, _Float16* __restrict__ mask_f) {
  int bx = blockIdx.x;
  int w  = blockIdx.y;
  int l  = threadIdx.x;
  int qt = bx >> 5, kt = bx & 31;
  int k  = kt*16 + (l & 15);
  int qb = qt*16 + (l >> 4)*4;
  const float* mp = mask + (size_t)w*262144;
  f16x4 v;
  #pragma unroll
  for (int r = 0; r < 4; ++r)
    v[r] = (_Float16)mp[(qb + r)*512 + k];
  *(f16x4*)(mask_f + ((size_t)(w*1024 + bx)*64 + l)*4) = v;
}

// ---------------- K4: QKV GEMM + bias + q/k row-norm + logit scale (fp16 out) ----------------
// x:[32768][192]  w:[576][192]  out: qn/kn/vv each [B*H][N][HD] fp16; qn pre-scaled
__global__ __launch_bounds__(192) void k_qkv(
    const float* __restrict__ x, const float* __restrict__ wq,
    const float* __restrict__ q_bias, const float* __restrict__ v_bias,
    const float* __restrict__ logit_scale,
    _Float16* __restrict__ qn, _Float16* __restrict__ kn, _Float16* __restrict__ vv) {
  __shared__ float xs[16][200];
  int t  = threadIdx.x;            // 0..191 = column within each part
  int m0 = blockIdx.x * 16;
  #pragma unroll
  for (int i = 0; i < 4; ++i) {
    int fid = t + i*192;
    int r = fid / 48, k = (fid % 48) * 4;
    *(float4*)(&xs[r][k]) = *(const float4*)(x + (size_t)(m0 + r)*192 + k);
  }
  __syncthreads();

  float acc[3][16];
  #pragma unroll
  for (int p = 0; p < 3; ++p)
    #pragma unroll
    for (int r = 0; r < 16; ++r) acc[p][r] = 0.f;

  for (int kc = 0; kc < 12; ++kc) {
    int k0 = kc * 16;
    float wr[3][16];
    #pragma unroll
    for (int p = 0; p < 3; ++p) {
      const float* wp = wq + (size_t)(p*192 + t)*192 + k0;
      float4 a0 = *(const float4*)(wp+0);
      float4 a1 = *(const float4*)(wp+4);
      float4 a2 = *(const float4*)(wp+8);
      float4 a3 = *(const float4*)(wp+12);
      wr[p][0]=a0.x; wr[p][1]=a0.y; wr[p][2]=a0.z; wr[p][3]=a0.w;
      wr[p][4]=a1.x; wr[p][5]=a1.y; wr[p][6]=a1.z; wr[p][7]=a1.w;
      wr[p][8]=a2.x; wr[p][9]=a2.y; wr[p][10]=a2.z; wr[p][11]=a2.w;
      wr[p][12]=a3.x; wr[p][13]=a3.y; wr[p][14]=a3.z; wr[p][15]=a3.w;
    }
    #pragma unroll
    for (int r = 0; r < 16; ++r) {
      float xk[16];
      float4 x0 = *(const float4*)(&xs[r][k0+0]);
      float4 x1 = *(const float4*)(&xs[r][k0+4]);
      float4 x2 = *(const float4*)(&xs[r][k0+8]);
      float4 x3 = *(const float4*)(&xs[r][k0+12]);
      xk[0]=x0.x; xk[1]=x0.y; xk[2]=x0.z; xk[3]=x0.w;
      xk[4]=x1.x; xk[5]=x1.y; xk[6]=x1.z; xk[7]=x1.w;
      xk[8]=x2.x; xk[9]=x2.y; xk[10]=x2.z; xk[11]=x2.w;
      xk[12]=x3.x; xk[13]=x3.y; xk[14]=x3.z; xk[15]=x3.w;
      #pragma unroll
      for (int p = 0; p < 3; ++p)
        #pragma unroll
        for (int kk = 0; kk < 16; ++kk)
          acc[p][r] = fmaf(xk[kk], wr[p][kk], acc[p][r]);
    }
  }

  int hh = t >> 5, d = t & 31;
  float scaleq = __expf(fminf(logit_scale[hh], 4.6051702f));
  float qb = q_bias[t], vb = v_bias[t];
  #pragma unroll
  for (int r = 0; r < 16; ++r) {
    int m = m0 + r;
    int bb = m >> 9, n = m & 511;
    size_t base = ((((size_t)bb*HEADS + hh)*NTOK) + n)*HD + d;
    float qv = acc[0][r] + qb;
    float kv = acc[1][r];
    float vval = acc[2][r] + vb;
    float ssq = qv*qv, ssk = kv*kv;
    #pragma unroll
    for (int off = 16; off > 0; off >>= 1) {
      ssq += __shfl_xor(ssq, off, 32);
      ssk += __shfl_xor(ssk, off, 32);
    }
    float invq = 1.f / fmaxf(sqrtf(ssq), 1e-12f);
    float invk = 1.f / fmaxf(sqrtf(ssk), 1e-12f);
    qn[base] = (_Float16)(qv * invq * scaleq);
    kn[base] = (_Float16)(kv * invk);
    vv[base] = (_Float16)vval;
  }
}

// ---------------- K5: transpose V -> vt[pair][32][512] fp16 ----------------
__global__ __launch_bounds__(256) void k_vt(
    const _Float16* __restrict__ vv, _Float16* __restrict__ vt) {
  __shared__ _Float16 lt[64][40];
  int nc = blockIdx.x;            // 0..7  (chunk of 64 tokens)
  int pair = blockIdx.y;          // 0..383
  int t = threadIdx.x;
  {
    int r = t >> 2, d0 = (t & 3) * 8;
    f16x8 v = *(const f16x8*)(vv + ((size_t)pair*512 + nc*64 + r)*32 + d0);
    *(f16x8*)(&lt[r][d0]) = v;
  }
  __syncthreads();
  {
    int d = t >> 3, n0 = (t & 7) * 8;
    f16x8 v;
    #pragma unroll
    for (int j = 0; j < 8; ++j) v[j] = lt[n0 + j][d];
    *(f16x8*)(vt + ((size_t)pair*32 + d)*512 + nc*64 + n0) = v;
  }
}

// ---------------- K6: MFMA flash attention ----------------
// grid (4 qblk, 6 h, 64 b), 256 thr = 4 waves, wave owns 32 q rows
__global__ __launch_bounds__(256) void k_attn(
    const _Float16* __restrict__ qn, const _Float16* __restrict__ kn,
    const _Float16* __restrict__ vt, const _Float16* __restrict__ bias_f,
    const _Float16* __restrict__ mask_f, float* __restrict__ out) {
  __shared__ _Float16 plds[4][32][88];
  int qblk = blockIdx.x, h = blockIdx.y, b = blockIdx.z;
  int w = b & (NW-1);
  int wid = threadIdx.x >> 6, l = threadIdx.x & 63;
  int lr = l & 15, lg = l >> 4;
  size_t pair = (size_t)b*HEADS + h;
  const _Float16* qb = qn + pair*NTOK*HD;
  const _Float16* kb = kn + pair*NTOK*HD;
  const _Float16* vb = vt + pair*HD*NTOK;
  const _Float16* bias_base = bias_f + (size_t)h*262144;   // 1024*64*4
  const _Float16* mask_base = mask_f + (size_t)w*262144;
  int q0 = qblk*128 + wid*32;
  int qtb = q0 >> 4;

  f16x8 aq[2];
  aq[0] = *(const f16x8*)(qb + (size_t)(q0 + lr)*HD + lg*8);
  aq[1] = *(const f16x8*)(qb + (size_t)(q0 + 16 + lr)*HD + lg*8);

  const f32x4 zero = {0.f, 0.f, 0.f, 0.f};
  f32x4 o[2][2];
  o[0][0] = zero; o[0][1] = zero; o[1][0] = zero; o[1][1] = zero;
  float mrun[2][4], lrun[2][4];
  #pragma unroll
  for (int mt = 0; mt < 2; ++mt)
    #pragma unroll
    for (int r = 0; r < 4; ++r) { mrun[mt][r] = -1e30f; lrun[mt][r] = 0.f; }

  for (int ch = 0; ch < 8; ++ch) {
    // ---- S = Q K^T
    f16x8 bk[4];
    #pragma unroll
    for (int nt = 0; nt < 4; ++nt)
      bk[nt] = *(const f16x8*)(kb + (size_t)(ch*64 + nt*16 + lr)*HD + lg*8);
    f32x4 s[2][4];
    #pragma unroll
    for (int mt = 0; mt < 2; ++mt)
      #pragma unroll
      for (int nt = 0; nt < 4; ++nt)
        s[mt][nt] = __builtin_amdgcn_mfma_f32_16x16x32_f16(aq[mt], bk[nt], zero, 0, 0, 0);
    // ---- + bias + mask (fragment-ordered tables)
    #pragma unroll
    for (int mt = 0; mt < 2; ++mt) {
      int qt = qtb + mt;
      #pragma unroll
      for (int nt = 0; nt < 4; ++nt) {
        int kt = ch*4 + nt;
        size_t toff = ((size_t)(qt*32 + kt)*64 + l)*4;
        f16x4 bf = *(const f16x4*)(bias_base + toff);
        f16x4 mf = *(const f16x4*)(mask_base + toff);
        #pragma unroll
        for (int r = 0; r < 4; ++r)
          s[mt][nt][r] += (float)bf[r] + (float)mf[r];
      }
    }
    // ---- online softmax (stats per q-row; cols live across lane bits 0..3)
    #pragma unroll
    for (int mt = 0; mt < 2; ++mt) {
      #pragma unroll
      for (int r = 0; r < 4; ++r) {
        float cm = fmaxf(fmaxf(s[mt][0][r], s[mt][1][r]), fmaxf(s[mt][2][r], s[mt][3][r]));
        cm = fmaxf(cm, __shfl_xor(cm, 1));
        cm = fmaxf(cm, __shfl_xor(cm, 2));
        cm = fmaxf(cm, __shfl_xor(cm, 4));
        cm = fmaxf(cm, __shfl_xor(cm, 8));
        float mold = mrun[mt][r];
        float mnew = fmaxf(mold, cm);
        float corr = __expf(mold - mnew);
        mrun[mt][r] = mnew;
        lrun[mt][r] *= corr;
        o[mt][0][r] *= corr;
        o[mt][1][r] *= corr;
        float rs = 0.f;
        #pragma unroll
        for (int nt = 0; nt < 4; ++nt) {
          float p = __expf(s[mt][nt][r] - mnew);
          s[mt][nt][r] = p;
          rs += p;
        }
        rs += __shfl_xor(rs, 1);
        rs += __shfl_xor(rs, 2);
        rs += __shfl_xor(rs, 4);
        rs += __shfl_xor(rs, 8);
        lrun[mt][r] += rs;
      }
    }
    // ---- P -> LDS (fp16), per-wave buffer, no cross-wave sync needed
    #pragma unroll
    for (int mt = 0; mt < 2; ++mt)
      #pragma unroll
      for (int nt = 0; nt < 4; ++nt)
        #pragma unroll
        for (int r = 0; r < 4; ++r)
          plds[wid][mt*16 + lg*4 + r][nt*16 + lr] = (_Float16)s[mt][nt][r];
    // ---- O += P V
    #pragma unroll
    for (int kk = 0; kk < 2; ++kk) {
      f16x8 ap0 = *(const f16x8*)(&plds[wid][lr][kk*32 + lg*8]);
      f16x8 ap1 = *(const f16x8*)(&plds[wid][16 + lr][kk*32 + lg*8]);
      #pragma unroll
      for (int dt = 0; dt < 2; ++dt) {
        f16x8 bv = *(const f16x8*)(vb + (size_t)(dt*16 + lr)*NTOK + ch*64 + kk*32 + lg*8);
        o[0][dt] = __builtin_amdgcn_mfma_f32_16x16x32_f16(ap0, bv, o[0][dt], 0, 0, 0);
        o[1][dt] = __builtin_amdgcn_mfma_f32_16x16x32_f16(ap1, bv, o[1][dt], 0, 0, 0);
      }
    }
  }
  // ---- epilogue: normalize + store fp32 to out[b][q][h*32+d]
  float* op = out + (size_t)b*NTOK*CDIM + (size_t)h*HD;
  #pragma unroll
  for (int mt = 0; mt < 2; ++mt) {
    #pragma unroll
    for (int r = 0; r < 4; ++r) {
      float inv = 1.f / lrun[mt][r];
      int qg = q0 + mt*16 + lg*4 + r;
      #pragma unroll
      for (int dt = 0; dt < 2; ++dt)
        op[(size_t)qg*CDIM + dt*16 + lr] = o[mt][dt][r] * inv;
    }
  }
}

// ---------------- K7: output projection, in-place on d_out ----------------
__global__ __launch_bounds__(192) void k_proj(
    float* __restrict__ a, const float* __restrict__ wp,
    const float* __restrict__ pb) {
  __shared__ float xs[32][200];
  int t  = threadIdx.x;
  int m0 = blockIdx.x * 32;
  #pragma unroll
  for (int i = 0; i < 8; ++i) {
    int fid = t + i*192;
    int r = fid / 48, k = (fid % 48) * 4;
    *(float4*)(&xs[r][k]) = *(const float4*)(a + (size_t)(m0 + r)*CDIM + k);
  }
  __syncthreads();

  int rg = t / 96;
  int c0 = t % 96;
  float acc[2][16];
  #pragma unroll
  for (int cc = 0; cc < 2; ++cc)
    #pragma unroll
    for (int r = 0; r < 16; ++r) acc[cc][r] = 0.f;

  for (int kc = 0; kc < 12; ++kc) {
    int k0 = kc * 16;
    float wr[2][16];
    #pragma unroll
    for (int cc = 0; cc < 2; ++cc) {
      const float* wrow = wp + (size_t)(c0 + cc*96)*CDIM + k0;
      float4 a0 = *(const float4*)(wrow+0);
      float4 a1 = *(const float4*)(wrow+4);
      float4 a2 = *(const float4*)(wrow+8);
      float4 a3 = *(const float4*)(wrow+12);
      wr[cc][0]=a0.x; wr[cc][1]=a0.y; wr[cc][2]=a0.z; wr[cc][3]=a0.w;
      wr[cc][4]=a1.x; wr[cc][5]=a1.y; wr[cc][6]=a1.z; wr[cc][7]=a1.w;
      wr[cc][8]=a2.x; wr[cc][9]=a2.y; wr[cc][10]=a2.z; wr[cc][11]=a2.w;
      wr[cc][12]=a3.x; wr[cc][13]=a3.y; wr[cc][14]=a3.z; wr[cc][15]=a3.w;
    }
    #pragma unroll
    for (int r = 0; r < 16; ++r) {
      int row = rg*16 + r;
      float xk[16];
      float4 x0 = *(const float4*)(&xs[row][k0+0]);
      float4 x1 = *(const float4*)(&xs[row][k0+4]);
      float4 x2 = *(const float4*)(&xs[row][k0+8]);
      float4 x3 = *(const float4*)(&xs[row][k0+12]);
      xk[0]=x0.x; xk[1]=x0.y; xk[2]=x0.z; xk[3]=x0.w;
      xk[4]=x1.x; xk[5]=x1.y; xk[6]=x1.z; xk[7]=x1.w;
      xk[8]=x2.x; xk[9]=x2.y; xk[10]=x2.z; xk[11]=x2.w;
      xk[12]=x3.x; xk[13]=x3.y; xk[14]=x3.z; xk[15]=x3.w;
      #pragma unroll
      for (int cc = 0; cc < 2; ++cc)
        #pragma unroll
        for (int kk = 0; kk < 16; ++kk)
          acc[cc][r] = fmaf(xk[kk], wr[cc][kk], acc[cc][r]);
    }
  }
  __syncthreads();
  #pragma unroll
  for (int cc = 0; cc < 2; ++cc) {
    int c = c0 + cc*96;
    float bias = pb[c];
    #pragma unroll
    for (int r = 0; r < 16; ++r) {
      int row = m0 + rg*16 + r;
      a[(size_t)row*CDIM + c] = acc[cc][r] + bias;
    }
  }
}

extern "C" void kernel_launch(void* const* d_in, const int* in_sizes, int n_in,
                              void* d_out, int out_size, void* d_ws, size_t ws_size,
                              hipStream_t stream) {
  const float* x           = (const float*)d_in[0];
  const float* mask        = (const float*)d_in[1];
  const float* qkv_w       = (const float*)d_in[2];
  const float* q_bias      = (const float*)d_in[3];
  const float* v_bias      = (const float*)d_in[4];
  const float* logit_scale = (const float*)d_in[5];
  const float* cpb_w1      = (const float*)d_in[6];
  const float* cpb_b1      = (const float*)d_in[7];
  const float* cpb_w2      = (const float*)d_in[8];
  const float* proj_w      = (const float*)d_in[9];
  const float* proj_b      = (const float*)d_in[10];
  const float* rel_table   = (const float*)d_in[11];
  const int*   rel_index   = (const int*)d_in[12];
  float* out = (float*)d_out;

  float* wsf = (float*)d_ws;
  float* tbl_t = wsf;                           // 6*3375 fp32, reserve 20480
  _Float16* hws    = (_Float16*)(wsf + 20480);
  _Float16* qn     = hws;                       // 384*512*32 = 6291456
  _Float16* kn     = qn + 6291456;
  _Float16* vv     = kn + 6291456;
  _Float16* vt     = vv + 6291456;
  _Float16* bias_f = vt + 6291456;              // 6*1024*64*4  = 1572864
  _Float16* mask_f = bias_f + 1572864;          // 16*1024*64*4 = 4194304
  // total ~62 MB

  k_cpb<<<T3, 512, 0, stream>>>(rel_table, cpb_w1, cpb_b1, cpb_w2, tbl_t);
  k_biasf<<<dim3(1024, HEADS), 64, 0, stream>>>(rel_index, tbl_t, bias_f);
  k_maskf<<<dim3(1024, NW), 64, 0, stream>>>(mask, mask_f);
  k_qkv<<<2048, 192, 0, stream>>>(x, qkv_w, q_bias, v_bias, logit_scale, qn, kn, vv);
  k_vt<<<dim3(8, 384), 256, 0, stream>>>(vv, vt);
  k_attn<<<dim3(4, HEADS, B__), 256, 0, stream>>>(qn, kn, vt, bias_f, mask_f, out);
  k_proj<<<1024, 192, 0, stream>>>(out, proj_w, proj_b);
}

// Round 4
// 279.018 us; speedup vs baseline: 2.0420x; 1.4709x over previous
//
#include <hip/hip_runtime.h>
#include <hip/hip_bf16.h>
#include <math.h>

#define B__ 64
#define NTOK 512
#define CDIM 192
#define HEADS 6
#define HD 32
#define NW 16
#define T3 3375
#define HID 512

typedef _Float16 f16x8 __attribute__((ext_vector_type(8)));
typedef _Float16 f16x4 __attribute__((ext_vector_type(4)));
typedef float    f32x4 __attribute__((ext_vector_type(4)));

// ---------------- K1: CPB MLP -> tbl_t[6][3375] (16*sigmoid applied) ----------------
__global__ __launch_bounds__(512) void k_cpb(
    const float* __restrict__ rel_table, const float* __restrict__ w1,
    const float* __restrict__ b1, const float* __restrict__ w2,
    float* __restrict__ tbl_t) {
  int i = blockIdx.x;          // table row 0..3374
  int t = threadIdx.x;         // hidden unit 0..511
  float t0 = rel_table[i*3+0], t1 = rel_table[i*3+1], t2 = rel_table[i*3+2];
  float hval = fmaxf(t0*w1[t*3+0] + t1*w1[t*3+1] + t2*w1[t*3+2] + b1[t], 0.f);
  __shared__ float red[8][6];
  int wv = t >> 6, lane = t & 63;
  #pragma unroll
  for (int hh = 0; hh < 6; ++hh) {
    float p = hval * w2[hh*HID + t];
    #pragma unroll
    for (int off = 32; off > 0; off >>= 1) p += __shfl_down(p, off);
    if (lane == 0) red[wv][hh] = p;
  }
  __syncthreads();
  if (t < 6) {
    float s = 0.f;
    #pragma unroll
    for (int w8 = 0; w8 < 8; ++w8) s += red[w8][t];
    tbl_t[t*T3 + i] = 16.f / (1.f + __expf(-s));
  }
}

// ---------------- K2: bias table -> MFMA-fragment layout, fp16 ----------------
__global__ __launch_bounds__(64) void k_biasf(
    const int* __restrict__ idx, const float* __restrict__ tbl_t,
    _Float16* __restrict__ bias_f) {
  int bx = blockIdx.x;              // qt*32+kt
  int h  = blockIdx.y;
  int l  = threadIdx.x;
  int qt = bx >> 5, kt = bx & 31;
  int k  = kt*16 + (l & 15);
  int qb = qt*16 + (l >> 4)*4;
  f16x4 v;
  #pragma unroll
  for (int r = 0; r < 4; ++r) {
    int id = idx[(qb + r)*512 + k];
    v[r] = (_Float16)tbl_t[h*T3 + id];
  }
  *(f16x4*)(bias_f + ((size_t)(h*1024 + bx)*64 + l)*4) = v;
}

// ---------------- K3: mask -> MFMA-fragment layout, fp16 ----------------
__global__ __launch_bounds__(64) void k_maskf(
    const float* __restrict__ mask, _Float16* __restrict__ mask_f) {
  int bx = blockIdx.x;
  int w  = blockIdx.y;
  int l  = threadIdx.x;
  int qt = bx >> 5, kt = bx & 31;
  int k  = kt*16 + (l & 15);
  int qb = qt*16 + (l >> 4)*4;
  const float* mp = mask + (size_t)w*262144;
  f16x4 v;
  #pragma unroll
  for (int r = 0; r < 4; ++r)
    v[r] = (_Float16)mp[(qb + r)*512 + k];
  *(f16x4*)(mask_f + ((size_t)(w*1024 + bx)*64 + l)*4) = v;
}

// ---------------- K4a: x fp32 -> fp16 ----------------
__global__ __launch_bounds__(256) void k_xh(
    const float* __restrict__ x, _Float16* __restrict__ xh) {
  int i = blockIdx.x*256 + threadIdx.x;     // 6144*256 = 1572864 float4 exactly
  float4 v = ((const float4*)x)[i];
  f16x4 h = {(_Float16)v.x, (_Float16)v.y, (_Float16)v.z, (_Float16)v.w};
  *(f16x4*)(xh + (size_t)i*4) = h;
}

// ---------------- K4b: weights fp32 -> fp16 (qkv_w then proj_w, contiguous) ----------------
__global__ __launch_bounds__(256) void k_wh(
    const float* __restrict__ qkv_w, const float* __restrict__ proj_w,
    _Float16* __restrict__ wh) {
  int i = blockIdx.x*256 + threadIdx.x;     // 144*256 = 36864 float4 exactly
  float4 v = (i < 27648) ? ((const float4*)qkv_w)[i] : ((const float4*)proj_w)[i - 27648];
  f16x4 h = {(_Float16)v.x, (_Float16)v.y, (_Float16)v.z, (_Float16)v.w};
  *(f16x4*)(wh + (size_t)i*4) = h;
}

// ---------------- K5: QKV GEMM via MFMA + bias + q/k row-norm + logit scale ----------------
// xh:[32768][192] fp16, wh(qkv):[576][192] fp16
// grid (256 row-blocks, 9 col-blocks), 256 thr = 4 waves; wave = 32 rows x 64 cols
__global__ __launch_bounds__(256) void k_qkv(
    const _Float16* __restrict__ xh, const _Float16* __restrict__ wh,
    const float* __restrict__ q_bias, const float* __restrict__ v_bias,
    const float* __restrict__ logit_scale,
    _Float16* __restrict__ qn, _Float16* __restrict__ kn, _Float16* __restrict__ vv) {
  int wid = threadIdx.x >> 6, l = threadIdx.x & 63;
  int lr = l & 15, lg = l >> 4;
  int m0 = blockIdx.x*128 + wid*32;
  int cb = blockIdx.y;
  int c0 = cb*64;
  int p  = cb/3;                    // 0=q 1=k 2=v
  int pc0 = (cb - p*3)*64;          // col offset within part
  int h0 = pc0 >> 5;                // first head of this tile

  const f32x4 zero = {0.f,0.f,0.f,0.f};
  f32x4 acc[2][4];
  #pragma unroll
  for (int mt = 0; mt < 2; ++mt)
    #pragma unroll
    for (int nt = 0; nt < 4; ++nt) acc[mt][nt] = zero;

  const _Float16* wb = wh + (size_t)c0*192;
  for (int kc = 0; kc < 6; ++kc) {
    int ko = kc*32 + lg*8;
    f16x8 a0 = *(const f16x8*)(xh + (size_t)(m0 + lr)*192 + ko);
    f16x8 a1 = *(const f16x8*)(xh + (size_t)(m0 + 16 + lr)*192 + ko);
    #pragma unroll
    for (int nt = 0; nt < 4; ++nt) {
      f16x8 bf = *(const f16x8*)(wb + (size_t)(nt*16 + lr)*192 + ko);
      acc[0][nt] = __builtin_amdgcn_mfma_f32_16x16x32_f16(a0, bf, acc[0][nt], 0, 0, 0);
      acc[1][nt] = __builtin_amdgcn_mfma_f32_16x16x32_f16(a1, bf, acc[1][nt], 0, 0, 0);
    }
  }

  // epilogue: C row = m0 + mt*16 + lg*4 + r, col = nt*16 + lr
  if (p == 0) {
    float bq[4];
    #pragma unroll
    for (int nt = 0; nt < 4; ++nt) bq[nt] = q_bias[pc0 + nt*16 + lr];
    float s0 = __expf(fminf(logit_scale[h0], 4.6051702f));
    float s1 = __expf(fminf(logit_scale[h0+1], 4.6051702f));
    #pragma unroll
    for (int mt = 0; mt < 2; ++mt) {
      #pragma unroll
      for (int nt = 0; nt < 4; ++nt)
        #pragma unroll
        for (int r = 0; r < 4; ++r) acc[mt][nt][r] += bq[nt];
      #pragma unroll
      for (int r = 0; r < 4; ++r) {
        float ss0 = acc[mt][0][r]*acc[mt][0][r] + acc[mt][1][r]*acc[mt][1][r];
        float ss1 = acc[mt][2][r]*acc[mt][2][r] + acc[mt][3][r]*acc[mt][3][r];
        #pragma unroll
        for (int off = 1; off < 16; off <<= 1) {
          ss0 += __shfl_xor(ss0, off);
          ss1 += __shfl_xor(ss1, off);
        }
        float inv0 = s0 / fmaxf(sqrtf(ss0), 1e-12f);
        float inv1 = s1 / fmaxf(sqrtf(ss1), 1e-12f);
        int m = m0 + mt*16 + lg*4 + r;
        int b = m >> 9, n = m & 511;
        #pragma unroll
        for (int nt = 0; nt < 4; ++nt) {
          int h = h0 + (nt >> 1);
          int d = (nt & 1)*16 + lr;
          float val = acc[mt][nt][r] * ((nt < 2) ? inv0 : inv1);
          qn[(((size_t)b*HEADS + h)*NTOK + n)*HD + d] = (_Float16)val;
        }
      }
    }
  } else if (p == 1) {
    #pragma unroll
    for (int mt = 0; mt < 2; ++mt) {
      #pragma unroll
      for (int r = 0; r < 4; ++r) {
        float ss0 = acc[mt][0][r]*acc[mt][0][r] + acc[mt][1][r]*acc[mt][1][r];
        float ss1 = acc[mt][2][r]*acc[mt][2][r] + acc[mt][3][r]*acc[mt][3][r];
        #pragma unroll
        for (int off = 1; off < 16; off <<= 1) {
          ss0 += __shfl_xor(ss0, off);
          ss1 += __shfl_xor(ss1, off);
        }
        float inv0 = 1.f / fmaxf(sqrtf(ss0), 1e-12f);
        float inv1 = 1.f / fmaxf(sqrtf(ss1), 1e-12f);
        int m = m0 + mt*16 + lg*4 + r;
        int b = m >> 9, n = m & 511;
        #pragma unroll
        for (int nt = 0; nt < 4; ++nt) {
          int h = h0 + (nt >> 1);
          int d = (nt & 1)*16 + lr;
          float val = acc[mt][nt][r] * ((nt < 2) ? inv0 : inv1);
          kn[(((size_t)b*HEADS + h)*NTOK + n)*HD + d] = (_Float16)val;
        }
      }
    }
  } else {
    float bv[4];
    #pragma unroll
    for (int nt = 0; nt < 4; ++nt) bv[nt] = v_bias[pc0 + nt*16 + lr];
    #pragma unroll
    for (int mt = 0; mt < 2; ++mt)
      #pragma unroll
      for (int r = 0; r < 4; ++r) {
        int m = m0 + mt*16 + lg*4 + r;
        int b = m >> 9, n = m & 511;
        #pragma unroll
        for (int nt = 0; nt < 4; ++nt) {
          int h = h0 + (nt >> 1);
          int d = (nt & 1)*16 + lr;
          vv[(((size_t)b*HEADS + h)*NTOK + n)*HD + d] = (_Float16)(acc[mt][nt][r] + bv[nt]);
        }
      }
  }
}

// ---------------- K6: transpose V -> vt[pair][32][512] fp16 ----------------
__global__ __launch_bounds__(256) void k_vt(
    const _Float16* __restrict__ vv, _Float16* __restrict__ vt) {
  __shared__ _Float16 lt[64][40];
  int nc = blockIdx.x;            // 0..7  (chunk of 64 tokens)
  int pair = blockIdx.y;          // 0..383
  int t = threadIdx.x;
  {
    int r = t >> 2, d0 = (t & 3) * 8;
    f16x8 v = *(const f16x8*)(vv + ((size_t)pair*512 + nc*64 + r)*32 + d0);
    *(f16x8*)(&lt[r][d0]) = v;
  }
  __syncthreads();
  {
    int d = t >> 3, n0 = (t & 7) * 8;
    f16x8 v;
    #pragma unroll
    for (int j = 0; j < 8; ++j) v[j] = lt[n0 + j][d];
    *(f16x8*)(vt + ((size_t)pair*32 + d)*512 + nc*64 + n0) = v;
  }
}

// ---------------- K7: MFMA flash attention (fp16 out to ao_h) ----------------
__global__ __launch_bounds__(256) void k_attn(
    const _Float16* __restrict__ qn, const _Float16* __restrict__ kn,
    const _Float16* __restrict__ vt, const _Float16* __restrict__ bias_f,
    const _Float16* __restrict__ mask_f, _Float16* __restrict__ ao_h) {
  __shared__ _Float16 plds[4][32][88];
  int qblk = blockIdx.x, h = blockIdx.y, b = blockIdx.z;
  int w = b & (NW-1);
  int wid = threadIdx.x >> 6, l = threadIdx.x & 63;
  int lr = l & 15, lg = l >> 4;
  size_t pair = (size_t)b*HEADS + h;
  const _Float16* qb = qn + pair*NTOK*HD;
  const _Float16* kb = kn + pair*NTOK*HD;
  const _Float16* vb = vt + pair*HD*NTOK;
  const _Float16* bias_base = bias_f + (size_t)h*262144;
  const _Float16* mask_base = mask_f + (size_t)w*262144;
  int q0 = qblk*128 + wid*32;
  int qtb = q0 >> 4;

  f16x8 aq[2];
  aq[0] = *(const f16x8*)(qb + (size_t)(q0 + lr)*HD + lg*8);
  aq[1] = *(const f16x8*)(qb + (size_t)(q0 + 16 + lr)*HD + lg*8);

  const f32x4 zero = {0.f, 0.f, 0.f, 0.f};
  f32x4 o[2][2];
  o[0][0] = zero; o[0][1] = zero; o[1][0] = zero; o[1][1] = zero;
  float mrun[2][4], lrun[2][4];
  #pragma unroll
  for (int mt = 0; mt < 2; ++mt)
    #pragma unroll
    for (int r = 0; r < 4; ++r) { mrun[mt][r] = -1e30f; lrun[mt][r] = 0.f; }

  for (int ch = 0; ch < 8; ++ch) {
    f16x8 bk[4];
    #pragma unroll
    for (int nt = 0; nt < 4; ++nt)
      bk[nt] = *(const f16x8*)(kb + (size_t)(ch*64 + nt*16 + lr)*HD + lg*8);
    f32x4 s[2][4];
    #pragma unroll
    for (int mt = 0; mt < 2; ++mt)
      #pragma unroll
      for (int nt = 0; nt < 4; ++nt)
        s[mt][nt] = __builtin_amdgcn_mfma_f32_16x16x32_f16(aq[mt], bk[nt], zero, 0, 0, 0);
    #pragma unroll
    for (int mt = 0; mt < 2; ++mt) {
      int qt = qtb + mt;
      #pragma unroll
      for (int nt = 0; nt < 4; ++nt) {
        int kt = ch*4 + nt;
        size_t toff = ((size_t)(qt*32 + kt)*64 + l)*4;
        f16x4 bf = *(const f16x4*)(bias_base + toff);
        f16x4 mf = *(const f16x4*)(mask_base + toff);
        #pragma unroll
        for (int r = 0; r < 4; ++r)
          s[mt][nt][r] += (float)bf[r] + (float)mf[r];
      }
    }
    #pragma unroll
    for (int mt = 0; mt < 2; ++mt) {
      #pragma unroll
      for (int r = 0; r < 4; ++r) {
        float cm = fmaxf(fmaxf(s[mt][0][r], s[mt][1][r]), fmaxf(s[mt][2][r], s[mt][3][r]));
        cm = fmaxf(cm, __shfl_xor(cm, 1));
        cm = fmaxf(cm, __shfl_xor(cm, 2));
        cm = fmaxf(cm, __shfl_xor(cm, 4));
        cm = fmaxf(cm, __shfl_xor(cm, 8));
        float mold = mrun[mt][r];
        float mnew = fmaxf(mold, cm);
        float corr = __expf(mold - mnew);
        mrun[mt][r] = mnew;
        lrun[mt][r] *= corr;
        o[mt][0][r] *= corr;
        o[mt][1][r] *= corr;
        float rs = 0.f;
        #pragma unroll
        for (int nt = 0; nt < 4; ++nt) {
          float p = __expf(s[mt][nt][r] - mnew);
          s[mt][nt][r] = p;
          rs += p;
        }
        rs += __shfl_xor(rs, 1);
        rs += __shfl_xor(rs, 2);
        rs += __shfl_xor(rs, 4);
        rs += __shfl_xor(rs, 8);
        lrun[mt][r] += rs;
      }
    }
    #pragma unroll
    for (int mt = 0; mt < 2; ++mt)
      #pragma unroll
      for (int nt = 0; nt < 4; ++nt)
        #pragma unroll
        for (int r = 0; r < 4; ++r)
          plds[wid][mt*16 + lg*4 + r][nt*16 + lr] = (_Float16)s[mt][nt][r];
    #pragma unroll
    for (int kk = 0; kk < 2; ++kk) {
      f16x8 ap0 = *(const f16x8*)(&plds[wid][lr][kk*32 + lg*8]);
      f16x8 ap1 = *(const f16x8*)(&plds[wid][16 + lr][kk*32 + lg*8]);
      #pragma unroll
      for (int dt = 0; dt < 2; ++dt) {
        f16x8 bv = *(const f16x8*)(vb + (size_t)(dt*16 + lr)*NTOK + ch*64 + kk*32 + lg*8);
        o[0][dt] = __builtin_amdgcn_mfma_f32_16x16x32_f16(ap0, bv, o[0][dt], 0, 0, 0);
        o[1][dt] = __builtin_amdgcn_mfma_f32_16x16x32_f16(ap1, bv, o[1][dt], 0, 0, 0);
      }
    }
  }
  _Float16* op = ao_h + (size_t)b*NTOK*CDIM + (size_t)h*HD;
  #pragma unroll
  for (int mt = 0; mt < 2; ++mt) {
    #pragma unroll
    for (int r = 0; r < 4; ++r) {
      float inv = 1.f / lrun[mt][r];
      int qg = q0 + mt*16 + lg*4 + r;
      #pragma unroll
      for (int dt = 0; dt < 2; ++dt)
        op[(size_t)qg*CDIM + dt*16 + lr] = (_Float16)(o[mt][dt][r] * inv);
    }
  }
}

// ---------------- K8: output projection via MFMA ----------------
// ao_h:[32768][192] fp16, pw:[192][192] fp16 -> out fp32 [32768][192]
__global__ __launch_bounds__(256) void k_proj(
    const _Float16* __restrict__ ao_h, const _Float16* __restrict__ pw,
    const float* __restrict__ pb, float* __restrict__ out) {
  int wid = threadIdx.x >> 6, l = threadIdx.x & 63;
  int lr = l & 15, lg = l >> 4;
  int m0 = blockIdx.x*128 + wid*32;
  int c0 = blockIdx.y*64;

  const f32x4 zero = {0.f,0.f,0.f,0.f};
  f32x4 acc[2][4];
  #pragma unroll
  for (int mt = 0; mt < 2; ++mt)
    #pragma unroll
    for (int nt = 0; nt < 4; ++nt) acc[mt][nt] = zero;

  for (int kc = 0; kc < 6; ++kc) {
    int ko = kc*32 + lg*8;
    f16x8 a0 = *(const f16x8*)(ao_h + (size_t)(m0 + lr)*192 + ko);
    f16x8 a1 = *(const f16x8*)(ao_h + (size_t)(m0 + 16 + lr)*192 + ko);
    #pragma unroll
    for (int nt = 0; nt < 4; ++nt) {
      f16x8 bf = *(const f16x8*)(pw + (size_t)(c0 + nt*16 + lr)*192 + ko);
      acc[0][nt] = __builtin_amdgcn_mfma_f32_16x16x32_f16(a0, bf, acc[0][nt], 0, 0, 0);
      acc[1][nt] = __builtin_amdgcn_mfma_f32_16x16x32_f16(a1, bf, acc[1][nt], 0, 0, 0);
    }
  }

  float bias[4];
  #pragma unroll
  for (int nt = 0; nt < 4; ++nt) bias[nt] = pb[c0 + nt*16 + lr];
  #pragma unroll
  for (int mt = 0; mt < 2; ++mt)
    #pragma unroll
    for (int r = 0; r < 4; ++r) {
      int m = m0 + mt*16 + lg*4 + r;
      #pragma unroll
      for (int nt = 0; nt < 4; ++nt)
        out[(size_t)m*CDIM + c0 + nt*16 + lr] = acc[mt][nt][r] + bias[nt];
    }
}

extern "C" void kernel_launch(void* const* d_in, const int* in_sizes, int n_in,
                              void* d_out, int out_size, void* d_ws, size_t ws_size,
                              hipStream_t stream) {
  const float* x           = (const float*)d_in[0];
  const float* mask        = (const float*)d_in[1];
  const float* qkv_w       = (const float*)d_in[2];
  const float* q_bias      = (const float*)d_in[3];
  const float* v_bias      = (const float*)d_in[4];
  const float* logit_scale = (const float*)d_in[5];
  const float* cpb_w1      = (const float*)d_in[6];
  const float* cpb_b1      = (const float*)d_in[7];
  const float* cpb_w2      = (const float*)d_in[8];
  const float* proj_w      = (const float*)d_in[9];
  const float* proj_b      = (const float*)d_in[10];
  const float* rel_table   = (const float*)d_in[11];
  const int*   rel_index   = (const int*)d_in[12];
  float* out = (float*)d_out;

  float* wsf = (float*)d_ws;
  float* tbl_t = wsf;                           // 6*3375 fp32, reserve 20480
  _Float16* hws    = (_Float16*)(wsf + 20480);
  _Float16* qn     = hws;                       // 384*512*32 = 6291456
  _Float16* kn     = qn + 6291456;
  _Float16* vv     = kn + 6291456;
  _Float16* vt     = vv + 6291456;
  _Float16* bias_f = vt + 6291456;              // 6*1024*64*4  = 1572864
  _Float16* mask_f = bias_f + 1572864;          // 16*1024*64*4 = 4194304
  _Float16* xh     = mask_f + 4194304;          // 32768*192    = 6291456
  _Float16* wh     = xh + 6291456;              // 576*192 + 192*192 = 147456
  _Float16* ao_h   = wh + 147456;               // 32768*192    = 6291456
  // total ~87.5 MB

  k_cpb<<<T3, 512, 0, stream>>>(rel_table, cpb_w1, cpb_b1, cpb_w2, tbl_t);
  k_biasf<<<dim3(1024, HEADS), 64, 0, stream>>>(rel_index, tbl_t, bias_f);
  k_maskf<<<dim3(1024, NW), 64, 0, stream>>>(mask, mask_f);
  k_xh<<<6144, 256, 0, stream>>>(x, xh);
  k_wh<<<144, 256, 0, stream>>>(qkv_w, proj_w, wh);
  k_qkv<<<dim3(256, 9), 256, 0, stream>>>(xh, wh, q_bias, v_bias, logit_scale, qn, kn, vv);
  k_vt<<<dim3(8, 384), 256, 0, stream>>>(vv, vt);
  k_attn<<<dim3(4, HEADS, B__), 256, 0, stream>>>(qn, kn, vt, bias_f, mask_f, ao_h);
  k_proj<<<dim3(256, 3), 256, 0, stream>>>(ao_h, wh + 110592, proj_b, out);
}